// Round 3
// baseline (448.761 us; speedup 1.0000x reference)
//
#include <hip/hip_runtime.h>
#include <hip/hip_bf16.h>
#include <math.h>

#define B_ 32768
#define F_ 512
#define H_ 256
#define C_ 100
#define CP 112   // C padded to 7*16 for MFMA m-tiles
#define E_ 8

typedef __attribute__((ext_vector_type(8))) short bf16x8;
typedef __attribute__((ext_vector_type(4))) float f32x4;

__device__ __forceinline__ unsigned short f2b(float f) {
    unsigned int u = __float_as_uint(f);
    return (unsigned short)((u + 0x7fffu + ((u >> 16) & 1u)) >> 16);
}

__device__ __forceinline__ void gll16(const void* g, void* l) {
    __builtin_amdgcn_global_load_lds((__attribute__((address_space(1))) void*)(g),
                                     (__attribute__((address_space(3))) void*)(l),
                                     16, 0, 0);
}

// ---------------- K0: fused x->bf16 convert + fp64 gating + top-2 + part_sizes ----
// Block = 8 rows x 32 threads/row. x read ONCE (was read twice by k0_cvt_x + k1_gate).
__global__ __launch_bounds__(256) void k0_gate(const float* __restrict__ x,
                                               const float* __restrict__ Wg,
                                               unsigned short* __restrict__ xb,
                                               int* __restrict__ routes,
                                               float* __restrict__ part) {
    __shared__ float sWgT[E_ * F_];   // [e][f], 16KB
    __shared__ int cnt[E_];
    const int tid = threadIdx.x;
    for (int i = tid; i < E_ * F_; i += 256) {
        int e = i & 7, f = i >> 3;
        sWgT[e * F_ + f] = Wg[i];
    }
    if (tid < E_) cnt[tid] = 0;
    __syncthreads();

    const int r = tid >> 5, c = tid & 31;
    const int row = blockIdx.x * 8 + r;
    const float* xr = x + (size_t)row * F_;
    double acc8[8];
    #pragma unroll
    for (int e = 0; e < 8; ++e) acc8[e] = 0.0;

    #pragma unroll
    for (int it = 0; it < 4; ++it) {
        int f0 = it * 128 + c * 4;
        float4 xv = *(const float4*)(xr + f0);
        ushort4 o;
        o.x = f2b(xv.x); o.y = f2b(xv.y); o.z = f2b(xv.z); o.w = f2b(xv.w);
        *(ushort4*)(xb + (size_t)row * F_ + f0) = o;
        #pragma unroll
        for (int e = 0; e < 8; ++e) {
            f32x4 wv = *(const f32x4*)(sWgT + e * F_ + f0);
            acc8[e] += (double)xv.x * (double)wv[0];
            acc8[e] += (double)xv.y * (double)wv[1];
            acc8[e] += (double)xv.z * (double)wv[2];
            acc8[e] += (double)xv.w * (double)wv[3];
        }
    }
    // reduce each expert over the 32 lanes of this row (xor <=16 stays in-group)
    #pragma unroll
    for (int off = 16; off; off >>= 1)
        #pragma unroll
        for (int e = 0; e < 8; ++e) acc8[e] += __shfl_xor(acc8[e], off);

    if (c == 0) {
        double best = -1e300, second = -1e300;
        int e1 = 0, e2 = 0;
        #pragma unroll
        for (int e = 0; e < 8; ++e) {
            double v = acc8[e];
            if (v > best) { second = best; e2 = e1; best = v; e1 = e; }
            else if (v > second) { second = v; e2 = e; }
        }
        routes[row] = e1 | (e2 << 3);
        atomicAdd(&cnt[e1], 1);
        atomicAdd(&cnt[e2], 1);
    }
    __syncthreads();
    if (tid < E_) atomicAdd(&part[tid], (float)cnt[tid]);
}

// ---------------- K0b: W1 [E][F][H] f32 -> W1t [E][H][F] bf16 ----------------
__global__ __launch_bounds__(256) void k0_tr_w1(const float* __restrict__ W1,
                                                unsigned short* __restrict__ w1t) {
    __shared__ float tile[32][33];
    int e = blockIdx.z, fb = blockIdx.x * 32, hb = blockIdx.y * 32;
    int tx = threadIdx.x, ty = threadIdx.y;
    #pragma unroll
    for (int j = 0; j < 4; ++j)
        tile[ty + 8 * j][tx] = W1[((size_t)(e * F_ + fb + ty + 8 * j)) * H_ + hb + tx];
    __syncthreads();
    #pragma unroll
    for (int j = 0; j < 4; ++j)
        w1t[((size_t)(e * H_ + hb + ty + 8 * j)) * F_ + fb + tx] = f2b(tile[tx][ty + 8 * j]);
}

// ---------------- K0c: W2 [E][H][C] f32 -> W2t [E][CP][H] bf16 (zero-padded) ----------------
__global__ __launch_bounds__(256) void k0_cvt_w2(const float* __restrict__ W2,
                                                 unsigned short* __restrict__ w2t) {
    int idx = blockIdx.x * 256 + threadIdx.x;
    if (idx >= E_ * CP * H_) return;
    int e = idx / (CP * H_);
    int r = idx - e * (CP * H_);
    int c = r / H_, h = r - c * H_;
    float v = (c < C_) ? W2[((size_t)(e * H_ + h)) * C_ + c] : 0.0f;
    w2t[idx] = f2b(v);
}

// ---------------- K2: fused per-expert MLP ----------------
// 256 thr (4 waves), 64 rows x expert e. BK=32, 16 iters. LDS = 32768 -> 5 blocks/CU.
// Role-swapped GEMM1: A = W1 (m=h), B = x (n=row) => C lane holds 4 consecutive h
// at fixed x-row -> packed ds_write_b64 epilogue into XOR-swizzled sH.
// LDS: sX [0,4096): 64 rows x 64B (4 chunks, slot=c^(r&3));
//      sW [4096,20480): 256 h x 64B (same swizzle);
//      sH overlays [0,32768): 64 rows x 512B, 16B-chunk slot = c ^ (row&7).
__global__ __launch_bounds__(256, 5) void k2_moe(const unsigned short* __restrict__ xbf,
                                                 const unsigned short* __restrict__ w1t,
                                                 const unsigned short* __restrict__ w2t,
                                                 const float* __restrict__ b1,
                                                 const float* __restrict__ b2,
                                                 float* __restrict__ preds) {
    __shared__ __align__(16) char smem[32768];
    const int tid = threadIdx.x;
    const int w = tid >> 6, lane = tid & 63;
    const int q = lane >> 4, ln = lane & 15;
    const int e = blockIdx.y;
    const int rowBase = blockIdx.x * 64;

    // staging: instr covers 64 chunks(16B) = 16 rows(64B each); lane l -> row sub l>>2,
    // dest slot l&3; source chunk j4 = slot ^ (row&3) = (l&3)^((l>>2)&3)
    const int sub = lane >> 2;
    const int j4 = (lane & 3) ^ (sub & 3);
    const unsigned short* srcA = xbf + (size_t)(rowBase + w * 16 + sub) * F_ + 8 * j4;
    const unsigned short* srcB = w1t + (size_t)(e * H_ + w * 16 + sub) * F_ + 8 * j4;
    char* dstA = smem + w * 1024;
    char* dstB = smem + 4096 + w * 1024;

    // bias over h (m-dim): h = w*64 + mt*16 + q*4 + r2
    f32x4 bias1v[4];
    #pragma unroll
    for (int mt = 0; mt < 4; ++mt)
        bias1v[mt] = *(const f32x4*)(b1 + e * H_ + w * 64 + mt * 16 + q * 4);

    f32x4 acc[4][4];
    #pragma unroll
    for (int i = 0; i < 4; ++i)
        #pragma unroll
        for (int j = 0; j < 4; ++j) acc[i][j] = (f32x4){0.f, 0.f, 0.f, 0.f};

    const int fsl = (q ^ (ln & 3)) * 16;     // fragment k-chunk slot offset
    for (int kk = 0; kk < 16; ++kk) {
        const int ko = kk * 32;
        gll16(srcA + ko, dstA);
        #pragma unroll
        for (int i = 0; i < 4; ++i)
            gll16(srcB + (size_t)i * 64 * F_ + ko, dstB + i * 4096);
        __syncthreads();
        bf16x8 af[4], bfr[4];
        #pragma unroll
        for (int mt = 0; mt < 4; ++mt)   // A = W1: h-row = w*64 + mt*16 + ln
            af[mt] = *(const bf16x8*)(smem + 4096 + (w * 64 + mt * 16 + ln) * 64 + fsl);
        #pragma unroll
        for (int nt = 0; nt < 4; ++nt)   // B = x: row = nt*16 + ln
            bfr[nt] = *(const bf16x8*)(smem + (nt * 16 + ln) * 64 + fsl);
        #pragma unroll
        for (int mt = 0; mt < 4; ++mt)
            #pragma unroll
            for (int nt = 0; nt < 4; ++nt)
                acc[mt][nt] = __builtin_amdgcn_mfma_f32_16x16x32_bf16(af[mt], bfr[nt], acc[mt][nt], 0, 0, 0);
        __syncthreads();
    }

    // epilogue: lane holds h = w*64+mt*16+q*4+{0..3} at x-row nt*16+ln -> packed b64
    #pragma unroll
    for (int mt = 0; mt < 4; ++mt) {
        const int ch = w * 8 + mt * 2 + (q >> 1);            // 16B chunk index of h0
        const int inner = (q & 1) * 8;
        #pragma unroll
        for (int nt = 0; nt < 4; ++nt) {
            const int xrow = nt * 16 + ln;
            float v0 = fmaxf(acc[mt][nt][0] + bias1v[mt][0], 0.0f);
            float v1 = fmaxf(acc[mt][nt][1] + bias1v[mt][1], 0.0f);
            float v2 = fmaxf(acc[mt][nt][2] + bias1v[mt][2], 0.0f);
            float v3 = fmaxf(acc[mt][nt][3] + bias1v[mt][3], 0.0f);
            uint2 pv;
            pv.x = (unsigned)f2b(v0) | ((unsigned)f2b(v1) << 16);
            pv.y = (unsigned)f2b(v2) | ((unsigned)f2b(v3) << 16);
            *(uint2*)(smem + xrow * 512 + ((ch ^ (xrow & 7)) * 16) + inner) = pv;
        }
    }

    // GEMM2: A = W2t[e] fragments from global (L2-hot, single-buffered; first kc
    // prefetched before the barrier), B = h from swizzled sH.
    const unsigned short* w2base = w2t + ((size_t)e * CP + ln) * H_ + q * 8;
    bf16x8 wreg[7];
    #pragma unroll
    for (int mt = 0; mt < 7; ++mt)
        wreg[mt] = *(const bf16x8*)(w2base + mt * 16 * H_);

    f32x4 acc2[7];
    #pragma unroll
    for (int i = 0; i < 7; ++i) acc2[i] = (f32x4){0.f, 0.f, 0.f, 0.f};
    const int hrow = w * 16 + ln;

    __syncthreads();   // sH fully written

    #pragma unroll
    for (int kc = 0; kc < 8; ++kc) {
        // B-frag: k-chunk = kc*4+q, row = hrow, swizzled slot
        bf16x8 hb = *(const bf16x8*)(smem + hrow * 512 + (((kc * 4 + q) ^ (hrow & 7)) * 16));
        #pragma unroll
        for (int mt = 0; mt < 7; ++mt)
            acc2[mt] = __builtin_amdgcn_mfma_f32_16x16x32_bf16(wreg[mt], hb, acc2[mt], 0, 0, 0);
        if (kc < 7) {
            #pragma unroll
            for (int mt = 0; mt < 7; ++mt)
                wreg[mt] = *(const bf16x8*)(w2base + mt * 16 * H_ + (kc + 1) * 32);
        }
    }

    // preds[e][row][c]: lane col = x-row = rowBase + w*16 + ln, rows = c = mt*16+q*4+r
    int row = rowBase + w * 16 + ln;
    #pragma unroll
    for (int mt = 0; mt < 7; ++mt) {
        int c0 = mt * 16 + q * 4;
        if (c0 + 3 < C_) {
            f32x4 bias = *(const f32x4*)(b2 + e * C_ + c0);
            f32x4 o = acc2[mt] + bias;
            *(f32x4*)(preds + ((size_t)e * B_ + row) * C_ + c0) = o;
        }
    }
}

// ---------------- K3: softmax(preds[e]) for routed experts, combine ----------------
__global__ __launch_bounds__(256) void k3_combine(const float* __restrict__ preds,
                                                  const int* __restrict__ routes,
                                                  float* __restrict__ combined) {
    __shared__ float pbuf[4][104];
    int tid = threadIdx.x, wv = tid >> 6, lane = tid & 63;
    int row = blockIdx.x * 2 + (wv >> 1);
    int rt = routes[row];
    int e = (wv & 1) ? ((rt >> 3) & 7) : (rt & 7);
    const float* pr = preds + ((size_t)e * B_ + row) * C_;
    float a0 = (lane < C_) ? pr[lane] : -1e30f;
    float a1 = (lane + 64 < C_) ? pr[lane + 64] : -1e30f;
    float m = fmaxf(a0, a1);
    #pragma unroll
    for (int off = 32; off; off >>= 1) m = fmaxf(m, __shfl_xor(m, off));
    float s0 = (lane < C_) ? expf(a0 - m) : 0.f;
    float s1 = (lane + 64 < C_) ? expf(a1 - m) : 0.f;
    float s = s0 + s1;
    #pragma unroll
    for (int off = 32; off; off >>= 1) s += __shfl_xor(s, off);
    float inv = 0.5f / s;
    if (lane < C_) pbuf[wv][lane] = s0 * inv;
    if (lane + 64 < C_) pbuf[wv][lane + 64] = s1 * inv;
    __syncthreads();
    if (tid < C_)
        combined[(size_t)(blockIdx.x * 2) * C_ + tid] = pbuf[0][tid] + pbuf[1][tid];
    else if (tid >= 128 && tid < 128 + C_)
        combined[(size_t)(blockIdx.x * 2 + 1) * C_ + (tid - 128)] = pbuf[2][tid - 128] + pbuf[3][tid - 128];
}

extern "C" void kernel_launch(void* const* d_in, const int* in_sizes, int n_in,
                              void* d_out, int out_size, void* d_ws, size_t ws_size,
                              hipStream_t stream) {
    (void)in_sizes; (void)n_in; (void)out_size;
    const float* x  = (const float*)d_in[0];
    const float* W1 = (const float*)d_in[1];
    const float* b1 = (const float*)d_in[2];
    const float* W2 = (const float*)d_in[3];
    const float* b2 = (const float*)d_in[4];
    const float* Wg = (const float*)d_in[5];
    // d_in[6] = k (always 2 per setup)

    float* out = (float*)d_out;
    float* combined = out;                                          // [B][C]
    float* preds = out + (size_t)B_ * C_;                           // [E][B][C]
    float* part  = out + (size_t)B_ * C_ + (size_t)E_ * B_ * C_;    // [E]

    char* ws = (char*)d_ws;
    unsigned short* xbf = (unsigned short*)ws;                      // 33,554,432 B
    unsigned short* w1t = (unsigned short*)(ws + 33554432);         //  2,097,152 B
    unsigned short* w2t = (unsigned short*)(ws + 35651584);         //    458,752 B
    int* routes = (int*)(ws + 36110336);                            //    131,072 B
    if (ws_size < 36241408) return;  // need ~36.3 MB scratch

    hipMemsetAsync(part, 0, E_ * sizeof(float), stream);
    k0_gate<<<B_ / 8, 256, 0, stream>>>(x, Wg, xbf, routes, part);
    k0_tr_w1<<<dim3(F_ / 32, H_ / 32, E_), dim3(32, 8), 0, stream>>>(W1, w1t);
    k0_cvt_w2<<<(E_ * CP * H_ + 255) / 256, 256, 0, stream>>>(W2, w2t);
    k2_moe<<<dim3(B_ / 64, E_), 256, 0, stream>>>(xbf, w1t, w2t, b1, b2, preds);
    k3_combine<<<B_ / 2, 256, 0, stream>>>(preds, routes, combined);
}